// Round 1
// baseline (384.933 us; speedup 1.0000x reference)
//
#include <hip/hip_runtime.h>
#include <math.h>

#define Lc   4096
#define Hc   1024
#define Bc   4
#define NNc  32     // NHALF modes
#define SUBc 64     // sub-chunk length
#define NSc  64     // Lc / SUBc sub-chunks per row

// Generic batched transpose: src[b][r][c] -> dst[b][c][r], 64x64 tiles.
__global__ __launch_bounds__(256) void transpose_bRC(const float* __restrict__ src,
                                                     float* __restrict__ dst,
                                                     int R, int C) {
    __shared__ float tile[64][65];
    int b  = blockIdx.z;
    int c0 = blockIdx.x * 64;
    int r0 = blockIdx.y * 64;
    int tx = threadIdx.x & 63;
    int ty = threadIdx.x >> 6;   // 0..3
    const float* s = src + (size_t)b * R * C;
    float*       d = dst + (size_t)b * R * C;
#pragma unroll
    for (int i = 0; i < 16; i++) {
        int r = i * 4 + ty;
        tile[r][tx] = s[(size_t)(r0 + r) * C + (c0 + tx)];
    }
    __syncthreads();
#pragma unroll
    for (int i = 0; i < 16; i++) {
        int c = i * 4 + ty;
        d[(size_t)(c0 + c) * R + (r0 + tx)] = tile[tx][c];
    }
}

// One block per (b,h) row of xT [B][H][L]. Writes yT in-place over xT.
__global__ __launch_bounds__(256) void s4d_main(
    const float* __restrict__ xT,
    float* __restrict__ yT,
    const float* __restrict__ log_dt,
    const float* __restrict__ log_A_real,
    const float* __restrict__ A_imag,
    const float* __restrict__ Cmat,    // [H][N][2]
    const float* __restrict__ Dvec)
{
    __shared__ float xs[Lc];               // 16 KB row
    __shared__ float WpR[NNc][SUBc];       // w^(t+1) table (SoA)
    __shared__ float WpI[NNc][SUBc];
    __shared__ float ER[NSc][NNc];         // sub-local states, then E = 2*Cw*G_carry
    __shared__ float EI[NSc][NNc];
    __shared__ float Ktap[SUBc];           // real taps (2*Re sum + D folded into tap 0)
    __shared__ float dAr[NNc], dAi[NNc], CwRs[NNc], CwIs[NNc], WSr[NNc], WSi[NNc];

    const int tid = threadIdx.x;
    const int bh  = blockIdx.x;            // b*H + h
    const int h   = bh & (Hc - 1);

    // stage row to LDS (coalesced float4)
    const float4* xr4 = (const float4*)(xT + (size_t)bh * Lc);
    float4* xs4 = (float4*)xs;
    for (int i = tid; i < Lc / 4; i += 256) xs4[i] = xr4[i];

    // per-mode constants
    if (tid < NNc) {
        int n = tid;
        float dt = expf(log_dt[h]);
        float Ar = -expf(log_A_real[h * NNc + n]);
        float Ai = A_imag[h * NNc + n];
        float ar = Ar * dt, ai = Ai * dt;          // dtA
        dAr[n] = ar; dAi[n] = ai;
        float er = expf(ar), sn, cs;
        sincosf(ai, &sn, &cs);
        float wr = er * cs, wi = er * sn;          // w = exp(dtA)
        float numr = wr - 1.f, numi = wi;          // exp(dtA)-1
        float inv = 1.f / (Ar * Ar + Ai * Ai);
        float fr = (numr * Ar + numi * Ai) * inv;  // (exp(dtA)-1)/A
        float fi = (numi * Ar - numr * Ai) * inv;
        float Ccr = Cmat[(h * NNc + n) * 2 + 0];
        float Cci = Cmat[(h * NNc + n) * 2 + 1];
        CwRs[n] = Ccr * fr - Cci * fi;
        CwIs[n] = Ccr * fi + Cci * fr;
        float er2 = expf(SUBc * ar), s2, c2;       // w^SUB = exp(SUB*dtA)
        sincosf(SUBc * ai, &s2, &c2);
        WSr[n] = er2 * c2; WSi[n] = er2 * s2;
    }
    __syncthreads();

    // power table Wp[n][t] = w^(t+1), computed directly via exp for accuracy
    for (int it = tid; it < NNc * SUBc; it += 256) {
        int n = it >> 6, t = it & 63;
        float ar = dAr[n] * (float)(t + 1);
        float ai = dAi[n] * (float)(t + 1);
        float er = expf(ar), sn, cs;
        sincosf(ai, &sn, &cs);
        WpR[n][t] = er * cs;
        WpI[n][t] = er * sn;
    }
    __syncthreads();

    // real taps K[j] = 2*Re(sum_n Cw * w^j); fold D into j=0
    if (tid < SUBc) {
        int j = tid;
        float acc = 0.f;
        if (j == 0) {
            for (int n = 0; n < NNc; n++) acc += CwRs[n];
        } else {
            for (int n = 0; n < NNc; n++)
                acc += CwRs[n] * WpR[n][j - 1] - CwIs[n] * WpI[n][j - 1];
        }
        acc *= 2.f;
        if (j == 0) acc += Dvec[h];
        Ktap[j] = acc;
    }

    // Phase A: sub-local states, S := w*S + x over each sub-chunk
    for (int k = 0; k < 8; k++) {
        int n = tid & 31;
        int s = (tid >> 5) + 8 * k;
        float wr = WpR[n][0], wi = WpI[n][0];
        const float* xp = &xs[s * SUBc];
        float Sr = 0.f, Si = 0.f;
#pragma unroll
        for (int j = 0; j < SUBc; j++) {
            float xv = xp[j];
            float nr = fmaf(wr, Sr, fmaf(-wi, Si, xv));
            float ni = fmaf(wi, Sr, wr * Si);
            Sr = nr; Si = ni;
        }
        ER[s][n] = Sr; EI[s][n] = Si;
    }
    __syncthreads();

    // sequential scan over sub-chunks: G carries; overwrite ER/EI with E = 2*Cw (x) G_prev
    if (tid < 32) {
        int n = tid;
        float Gr = 0.f, Gi = 0.f;
        float wsr_ = WSr[n], wsi_ = WSi[n];
        float cwr = 2.f * CwRs[n], cwi = 2.f * CwIs[n];
        for (int s = 0; s < NSc; s++) {
            float Sr = ER[s][n], Si = EI[s][n];
            ER[s][n] = fmaf(cwr, Gr, -(cwi * Gi));
            EI[s][n] = fmaf(cwr, Gi, (cwi * Gr));
            float nr = fmaf(wsr_, Gr, fmaf(-wsi_, Gi, Sr));
            float ni = fmaf(wsi_, Gr, fmaf(wsr_, Gi, Si));
            Gr = nr; Gi = ni;
        }
    }
    __syncthreads();

    // Phase B: outputs. wave handles one sub s (lanes = t), loop covers all subs.
    float* yrow = yT + (size_t)bh * Lc;
    for (int k = 0; k < 16; k++) {
        int s = (tid >> 6) + 4 * k;
        int t = tid & 63;
        const float* xp = &xs[s * SUBc];
        float acc = 0.f;
#pragma unroll 8
        for (int j = 0; j < SUBc; j++) {
            float xv = (j <= t) ? xp[t - j] : 0.f;
            acc = fmaf(Ktap[j], xv, acc);
        }
        float acc2 = 0.f;
#pragma unroll 8
        for (int n = 0; n < NNc; n++) {
            acc2 = fmaf(WpR[n][t], ER[s][n], acc2);
            acc2 = fmaf(-WpI[n][t], EI[s][n], acc2);
        }
        yrow[s * SUBc + t] = acc + acc2;
    }
}

extern "C" void kernel_launch(void* const* d_in, const int* in_sizes, int n_in,
                              void* d_out, int out_size, void* d_ws, size_t ws_size,
                              hipStream_t stream) {
    const float* x          = (const float*)d_in[0];
    const float* log_dt     = (const float*)d_in[1];
    const float* log_A_real = (const float*)d_in[2];
    const float* A_imag     = (const float*)d_in[3];
    const float* Cmat       = (const float*)d_in[4];
    const float* Dvec       = (const float*)d_in[5];
    float* out = (float*)d_out;
    float* ws  = (float*)d_ws;

    const size_t need = (size_t)Bc * Hc * Lc * sizeof(float);   // 64 MiB for xT/yT
    if (ws_size < need) return;  // scratch too small -> loud validation failure

    // x [B][L][H] -> ws (xT) [B][H][L]
    transpose_bRC<<<dim3(Hc / 64, Lc / 64, Bc), 256, 0, stream>>>(x, ws, Lc, Hc);
    // fused SSM per row; writes yT in-place over xT
    s4d_main<<<Bc * Hc, 256, 0, stream>>>(ws, ws, log_dt, log_A_real, A_imag, Cmat, Dvec);
    // ws (yT) [B][H][L] -> out [B][L][H]
    transpose_bRC<<<dim3(Lc / 64, Hc / 64, Bc), 256, 0, stream>>>(ws, out, Hc, Lc);
}

// Round 2
// 104.117 us; speedup vs baseline: 3.6971x; 3.6971x over previous
//
#include <hip/hip_runtime.h>
#include <math.h>

#define Lc 4096
#define Hc 1024
#define Bc 4
#define NNc 32

typedef __attribute__((ext_vector_type(8))) short s8v;
typedef __attribute__((ext_vector_type(4))) float f4v;

// swizzled element index for [64][64] bf16 matrix (rows 128B): XOR 16B slot by row&7
#define SWB(r, e) ((((r) << 6) + (e)) ^ (((r) & 7) << 3))
// swizzled element index for [64][64] fp32 matrix (rows 256B): XOR 16B slot by row&7
#define SWF(r, e) ((((r) << 6) + (e)) ^ (((r) & 7) << 2))

__device__ inline unsigned short bf16_rne(float x) {
    unsigned u = __float_as_uint(x);
    unsigned r = (u + 0x7FFFu + ((u >> 16) & 1u)) >> 16;
    return (unsigned short)r;
}
__device__ inline void split2(float x, unsigned short* h, unsigned short* l) {
    unsigned short hb = bf16_rne(x);
    *h = hb;
    float hf = __uint_as_float(((unsigned)hb) << 16);
    *l = bf16_rne(x - hf);
}
__device__ inline void cvt8(float4 a, float4 b, s8v* hi, s8v* lo) {
    float v[8] = {a.x, a.y, a.z, a.w, b.x, b.y, b.z, b.w};
    s8v h, l2;
#pragma unroll
    for (int i = 0; i < 8; i++) {
        unsigned short hh, ll;
        split2(v[i], &hh, &ll);
        h[i] = (short)hh; l2[i] = (short)ll;
    }
    *hi = h; *lo = l2;
}

// Generic batched transpose: src[b][r][c] -> dst[b][c][r], 64x64 tiles.
__global__ __launch_bounds__(256) void transpose_bRC(const float* __restrict__ src,
                                                     float* __restrict__ dst,
                                                     int R, int C) {
    __shared__ float tile[64][65];
    int b  = blockIdx.z;
    int c0 = blockIdx.x * 64;
    int r0 = blockIdx.y * 64;
    int tx = threadIdx.x & 63;
    int ty = threadIdx.x >> 6;
    const float* s = src + (size_t)b * R * C;
    float*       d = dst + (size_t)b * R * C;
#pragma unroll
    for (int i = 0; i < 16; i++) {
        int r = i * 4 + ty;
        tile[r][tx] = s[(size_t)(r0 + r) * C + (c0 + tx)];
    }
    __syncthreads();
#pragma unroll
    for (int i = 0; i < 16; i++) {
        int c = i * 4 + ty;
        d[(size_t)(c0 + c) * R + (r0 + tx)] = tile[tx][c];
    }
}

#define MFMA(a, b, c) __builtin_amdgcn_mfma_f32_16x16x32_bf16((a), (b), (c), 0, 0, 0)

// One block per h; processes all 4 batches. xT [B][H][L] in/out (yT overwrites).
__global__ __launch_bounds__(256, 2) void s4d_mfma(
    float* __restrict__ xT,
    const float* __restrict__ log_dt,
    const float* __restrict__ log_A_real,
    const float* __restrict__ A_imag,
    const float* __restrict__ Cmat,
    const float* __restrict__ Dvec)
{
    // B-operand matrices, stored transposed [out-col][k], bf16 hi/lo, swizzled
    __shared__ __align__(16) unsigned short WtH[4096], WtL[4096];  // S = X * Wrev
    __shared__ __align__(16) unsigned short TtH[4096], TtL[4096];  // toeplitz taps
    __shared__ __align__(16) unsigned short WpH[4096], WpL[4096];  // carry powers
    __shared__ __align__(16) float Slds[4096];                     // S then E, swizzled
    __shared__ float Kpart[64][4];
    __shared__ float Ktap[64];
    __shared__ float cAr[NNc], cAi[NNc], c2R[NNc], c2I[NNc], cWSr[NNc], cWSi[NNc];

    const int tid = threadIdx.x;
    const int h   = blockIdx.x;
    const int w   = tid >> 6;     // wave id: owns output rows 16w..16w+15
    const int l   = tid & 63;
    const int l15 = l & 15;
    const int grp = l >> 4;       // k-group / D-row group

    // ---- per-mode constants ----
    if (tid < NNc) {
        int n = tid;
        float dtv = expf(log_dt[h]);
        float Ar = -expf(log_A_real[h * NNc + n]);
        float Ai = A_imag[h * NNc + n];
        float ar = Ar * dtv, ai = Ai * dtv;
        cAr[n] = ar; cAi[n] = ai;
        float er = expf(ar), sn, cs;
        sincosf(ai, &sn, &cs);
        float numr = er * cs - 1.f, numi = er * sn;
        float inv = 1.f / (Ar * Ar + Ai * Ai);
        float fr = (numr * Ar + numi * Ai) * inv;
        float fi = (numi * Ar - numr * Ai) * inv;
        float Ccr = Cmat[(h * NNc + n) * 2 + 0];
        float Cci = Cmat[(h * NNc + n) * 2 + 1];
        c2R[n] = 2.f * (Ccr * fr - Cci * fi);   // 2*Re(Cw)
        c2I[n] = 2.f * (Ccr * fi + Cci * fr);   // 2*Im(Cw)
        float e64 = expf(64.f * ar), s64, c64;
        sincosf(64.f * ai, &s64, &c64);
        cWSr[n] = e64 * c64; cWSi[n] = e64 * s64;  // w^64
    }
    __syncthreads();

    // early X load for b=0 (hides under matrix generation)
    float4 rx0, rx1, rx2, rx3;
    {
        const float* xp = xT + (size_t)(0 * Hc + h) * Lc + (16 * w + l15) * 64;
        rx0 = *(const float4*)(xp + 8 * grp);
        rx1 = *(const float4*)(xp + 8 * grp + 4);
        rx2 = *(const float4*)(xp + 32 + 8 * grp);
        rx3 = *(const float4*)(xp + 36 + 8 * grp);
    }

    // ---- K-tap partial sums: tap p = tid>>2, mode-octet q = tid&3 ----
    {
        int p = tid >> 2, q = tid & 3;
        float acc = 0.f;
#pragma unroll
        for (int i = 0; i < 8; i++) {
            int n = 8 * q + i;
            float e = expf(cAr[n] * (float)p), sn, cs;
            sincosf(cAi[n] * (float)p, &sn, &cs);
            acc += e * (c2R[n] * cs - c2I[n] * sn);
        }
        Kpart[p][q] = acc;
    }

    // ---- generate Wt (row c, k=j: w_n^{63-j}) and Wp (row t, k=c: +/-w^{t+1}) ----
#pragma unroll
    for (int m = 0; m < 2; m++) {
        int u = tid + 256 * m;
        int r = u >> 3, jc = u & 7;
        {   // Wt row r=c: mode n=r>>1, re/im by r&1
            int n = r >> 1, im = r & 1;
            float ar = cAr[n], ai = cAi[n];
            s8v hv, lv;
#pragma unroll
            for (int i = 0; i < 8; i++) {
                float p = (float)(63 - (jc * 8 + i));
                float e = expf(ar * p), sn, cs;
                sincosf(ai * p, &sn, &cs);
                unsigned short hh, ll;
                split2(e * (im ? sn : cs), &hh, &ll);
                hv[i] = (short)hh; lv[i] = (short)ll;
            }
            int idx = SWB(r, jc * 8);
            *(s8v*)&WtH[idx] = hv;
            *(s8v*)&WtL[idx] = lv;
        }
        {   // Wp row r=t: col c: Re(w^{t+1}) / -Im(w^{t+1})
            float p = (float)(r + 1);
            s8v hv, lv;
#pragma unroll
            for (int i = 0; i < 8; i++) {
                int c = jc * 8 + i;
                int n = c >> 1;
                float e = expf(cAr[n] * p), sn, cs;
                sincosf(cAi[n] * p, &sn, &cs);
                float val = e * ((c & 1) ? -sn : cs);
                unsigned short hh, ll;
                split2(val, &hh, &ll);
                hv[i] = (short)hh; lv[i] = (short)ll;
            }
            int idx = SWB(r, jc * 8);
            *(s8v*)&WpH[idx] = hv;
            *(s8v*)&WpL[idx] = lv;
        }
    }
    __syncthreads();

    if (tid < 64) {
        float k = Kpart[tid][0] + Kpart[tid][1] + Kpart[tid][2] + Kpart[tid][3];
        if (tid == 0) k += Dvec[h];
        Ktap[tid] = k;
    }
    __syncthreads();

    // ---- generate Tt: row t, k=j: K[t-j] for j<=t ----
#pragma unroll
    for (int m = 0; m < 2; m++) {
        int u = tid + 256 * m;
        int r = u >> 3, jc = u & 7;
        s8v hv, lv;
#pragma unroll
        for (int i = 0; i < 8; i++) {
            int j = jc * 8 + i;
            float val = (j <= r) ? Ktap[r - j] : 0.f;
            unsigned short hh, ll;
            split2(val, &hh, &ll);
            hv[i] = (short)hh; lv[i] = (short)ll;
        }
        int idx = SWB(r, jc * 8);
        *(s8v*)&TtH[idx] = hv;
        *(s8v*)&TtL[idx] = lv;
    }
    __syncthreads();

    // ---- batch loop ----
    for (int b = 0; b < Bc; b++) {
        s8v xh0, xl0, xh1, xl1;
        cvt8(rx0, rx1, &xh0, &xl0);
        cvt8(rx2, rx3, &xh1, &xl1);

        // prefetch next batch's X (regs now free)
        if (b < Bc - 1) {
            const float* xp = xT + (size_t)((b + 1) * Hc + h) * Lc + (16 * w + l15) * 64;
            rx0 = *(const float4*)(xp + 8 * grp);
            rx1 = *(const float4*)(xp + 8 * grp + 4);
            rx2 = *(const float4*)(xp + 32 + 8 * grp);
            rx3 = *(const float4*)(xp + 36 + 8 * grp);
        }

        // Phase 1: S = X * Wrev   (bf16x3)
        f4v acc[4];
#pragma unroll
        for (int tj = 0; tj < 4; tj++) {
            int row = tj * 16 + l15;
            int i0 = SWB(row, 8 * grp);
            int i1 = SWB(row, 32 + 8 * grp);
            s8v bh0 = *(const s8v*)&WtH[i0];
            s8v bh1 = *(const s8v*)&WtH[i1];
            s8v bl0 = *(const s8v*)&WtL[i0];
            s8v bl1 = *(const s8v*)&WtL[i1];
            f4v a = {0.f, 0.f, 0.f, 0.f};
            a = MFMA(xh0, bh0, a);
            a = MFMA(xh1, bh1, a);
            a = MFMA(xl0, bh0, a);
            a = MFMA(xl1, bh1, a);
            a = MFMA(xh0, bl0, a);
            a = MFMA(xh1, bl1, a);
            acc[tj] = a;
        }
        // store S to LDS (D-layout: row=16w+4*grp+r2, col=tj*16+l15)
#pragma unroll
        for (int tj = 0; tj < 4; tj++) {
#pragma unroll
            for (int r2 = 0; r2 < 4; r2++) {
                int sr = 16 * w + 4 * grp + r2;
                Slds[SWF(sr, tj * 16 + l15)] = acc[tj][r2];
            }
        }
        __syncthreads();

        // carry scan: G_{s+1} = w^64 G_s + S_s ; E_s = 2Cw * G_s (into Slds)
        if (tid < NNc) {
            int n = tid;
            float Gr = 0.f, Gi = 0.f;
            const float wsr = cWSr[n], wsi = cWSi[n];
            const float cr = c2R[n], ci = c2I[n];
            for (int s = 0; s < 64; s++) {
                int x0 = ((s << 6) + 2 * n) ^ ((s & 7) << 2);
                float Sr = Slds[x0], Si = Slds[x0 + 1];
                Slds[x0]     = fmaf(cr, Gr, -(ci * Gi));
                Slds[x0 + 1] = fmaf(cr, Gi,  (ci * Gr));
                float nr = fmaf(wsr, Gr, fmaf(-wsi, Gi, Sr));
                float ni = fmaf(wsi, Gr, fmaf( wsr, Gi, Si));
                Gr = nr; Gi = ni;
            }
        }
        __syncthreads();

        // E fragments (A-operand rows = 16w+l15)
        s8v eh0, el0, eh1, el1;
        {
            int er = 16 * w + l15;
            int eb = er << 6, es = (er & 7) << 2;
            f4v e0 = *(const f4v*)&Slds[(eb + 8 * grp) ^ es];
            f4v e1 = *(const f4v*)&Slds[(eb + 8 * grp + 4) ^ es];
            f4v e2 = *(const f4v*)&Slds[(eb + 32 + 8 * grp) ^ es];
            f4v e3 = *(const f4v*)&Slds[(eb + 36 + 8 * grp) ^ es];
            float4 f0 = {e0[0], e0[1], e0[2], e0[3]};
            float4 f1 = {e1[0], e1[1], e1[2], e1[3]};
            float4 f2 = {e2[0], e2[1], e2[2], e2[3]};
            float4 f3 = {e3[0], e3[1], e3[2], e3[3]};
            cvt8(f0, f1, &eh0, &el0);
            cvt8(f2, f3, &eh1, &el1);
        }

        // Phase 3: Y = X*T + E*Wp  (bf16x3 each)
        float* yp = xT + (size_t)(b * Hc + h) * Lc;
#pragma unroll
        for (int tj = 0; tj < 4; tj++) {
            int row = tj * 16 + l15;
            int i0 = SWB(row, 8 * grp);
            int i1 = SWB(row, 32 + 8 * grp);
            s8v th0 = *(const s8v*)&TtH[i0];
            s8v th1 = *(const s8v*)&TtH[i1];
            s8v tl0 = *(const s8v*)&TtL[i0];
            s8v tl1 = *(const s8v*)&TtL[i1];
            s8v ph0 = *(const s8v*)&WpH[i0];
            s8v ph1 = *(const s8v*)&WpH[i1];
            s8v pl0 = *(const s8v*)&WpL[i0];
            s8v pl1 = *(const s8v*)&WpL[i1];
            f4v a = {0.f, 0.f, 0.f, 0.f};
            a = MFMA(xh0, th0, a);
            a = MFMA(xh1, th1, a);
            a = MFMA(xl0, th0, a);
            a = MFMA(xl1, th1, a);
            a = MFMA(xh0, tl0, a);
            a = MFMA(xh1, tl1, a);
            a = MFMA(eh0, ph0, a);
            a = MFMA(eh1, ph1, a);
            a = MFMA(el0, ph0, a);
            a = MFMA(el1, ph1, a);
            a = MFMA(eh0, pl0, a);
            a = MFMA(eh1, pl1, a);
#pragma unroll
            for (int r2 = 0; r2 < 4; r2++) {
                yp[(16 * w + 4 * grp + r2) * 64 + tj * 16 + l15] = a[r2];
            }
        }
        __syncthreads();   // Slds free for next batch
    }
}

extern "C" void kernel_launch(void* const* d_in, const int* in_sizes, int n_in,
                              void* d_out, int out_size, void* d_ws, size_t ws_size,
                              hipStream_t stream) {
    const float* x          = (const float*)d_in[0];
    const float* log_dt     = (const float*)d_in[1];
    const float* log_A_real = (const float*)d_in[2];
    const float* A_imag     = (const float*)d_in[3];
    const float* Cmat       = (const float*)d_in[4];
    const float* Dvec       = (const float*)d_in[5];
    float* out = (float*)d_out;
    float* ws  = (float*)d_ws;

    const size_t need = (size_t)Bc * Hc * Lc * sizeof(float);   // 64 MiB
    if (ws_size < need) return;

    // x [B][L][H] -> ws (xT) [B][H][L]
    transpose_bRC<<<dim3(Hc / 64, Lc / 64, Bc), 256, 0, stream>>>(x, ws, Lc, Hc);
    // fused SSM per h (all batches); writes yT in place
    s4d_mfma<<<Hc, 256, 0, stream>>>(ws, log_dt, log_A_real, A_imag, Cmat, Dvec);
    // ws (yT) [B][H][L] -> out [B][L][H]
    transpose_bRC<<<dim3(Lc / 64, Hc / 64, Bc), 256, 0, stream>>>(ws, out, Hc, Lc);
}

// Round 3
// 99.436 us; speedup vs baseline: 3.8711x; 1.0471x over previous
//
#include <hip/hip_runtime.h>
#include <math.h>

#define Lc 4096
#define Hc 1024
#define Bc 4
#define NNc 32

typedef __attribute__((ext_vector_type(8))) short s8v;
typedef __attribute__((ext_vector_type(4))) float f4v;

// swizzled element index for [64][64] bf16 matrix (rows 128B): XOR 16B slot by row&7
#define SWB(r, e) ((((r) << 6) + (e)) ^ (((r) & 7) << 3))

__device__ inline unsigned short bf16_rne(float x) {
    unsigned u = __float_as_uint(x);
    unsigned r = (u + 0x7FFFu + ((u >> 16) & 1u)) >> 16;
    return (unsigned short)r;
}
__device__ inline void split2(float x, unsigned short* h, unsigned short* l) {
    unsigned short hb = bf16_rne(x);
    *h = hb;
    float hf = __uint_as_float(((unsigned)hb) << 16);
    *l = bf16_rne(x - hf);
}
__device__ inline void cvt8(float4 a, float4 b, s8v* hi, s8v* lo) {
    float v[8] = {a.x, a.y, a.z, a.w, b.x, b.y, b.z, b.w};
    s8v h, l2;
#pragma unroll
    for (int i = 0; i < 8; i++) {
        unsigned short hh, ll;
        split2(v[i], &hh, &ll);
        h[i] = (short)hh; l2[i] = (short)ll;
    }
    *hi = h; *lo = l2;
}

// Batched 64x64-tile transpose, float4 global accesses, 65-pad LDS (2-way free).
__global__ __launch_bounds__(256) void transpose_v4(const float* __restrict__ src,
                                                    float* __restrict__ dst,
                                                    int R, int C) {
    __shared__ float tile[64][65];
    int b  = blockIdx.z;
    int c0 = blockIdx.x * 64;
    int r0 = blockIdx.y * 64;
    const float* s = src + (size_t)b * R * C;
    float*       d = dst + (size_t)b * R * C;
    int tid = threadIdx.x;
#pragma unroll
    for (int it = 0; it < 4; it++) {
        int idx = tid + 256 * it;
        int r = idx >> 4, c4 = idx & 15;
        float4 v = *(const float4*)(s + (size_t)(r0 + r) * C + (c0 + 4 * c4));
        tile[r][4 * c4 + 0] = v.x;
        tile[r][4 * c4 + 1] = v.y;
        tile[r][4 * c4 + 2] = v.z;
        tile[r][4 * c4 + 3] = v.w;
    }
    __syncthreads();
#pragma unroll
    for (int it = 0; it < 4; it++) {
        int idx = tid + 256 * it;
        int cc = idx >> 4, r4 = idx & 15;
        float4 v;
        v.x = tile[4 * r4 + 0][cc];
        v.y = tile[4 * r4 + 1][cc];
        v.z = tile[4 * r4 + 2][cc];
        v.w = tile[4 * r4 + 3][cc];
        *(float4*)(d + (size_t)(c0 + cc) * R + (r0 + 4 * r4)) = v;
    }
}

#define MFMA(a, b, c) __builtin_amdgcn_mfma_f32_16x16x32_bf16((a), (b), (c), 0, 0, 0)

// One block per h; 4 batches. xT [B][H][L] in/out (yT overwrites).
__global__ __launch_bounds__(256, 3) void s4d_mfma2(
    float* __restrict__ xT,
    const float* __restrict__ log_dt,
    const float* __restrict__ log_A_real,
    const float* __restrict__ A_imag,
    const float* __restrict__ Cmat,
    const float* __restrict__ Dvec)
{
    __shared__ __align__(16) unsigned short WtH[4096], WtL[4096];  // S = X*Wrev (hi/lo)
    __shared__ __align__(16) unsigned short TtH[4096];             // toeplitz taps (hi)
    __shared__ __align__(16) unsigned short WpH[4096];             // carry powers (hi)
    __shared__ float Sscan[64 * 65];   // [mode-comp][chunk], 65-pad; also Kpart scratch
    __shared__ float Ktap[64];
    __shared__ float cAr[NNc], cAi[NNc], c2R[NNc], c2I[NNc], cWSr[NNc], cWSi[NNc];

    const int tid = threadIdx.x;
    const int h   = blockIdx.x;
    const int w   = tid >> 6;
    const int l   = tid & 63;
    const int l15 = l & 15;
    const int grp = l >> 4;

    // early X load for b=0 (hides under table generation)
    float4 rx0, rx1, rx2, rx3;
    {
        const float* xp = xT + (size_t)(0 * Hc + h) * Lc + (16 * w + l15) * 64;
        rx0 = *(const float4*)(xp + 8 * grp);
        rx1 = *(const float4*)(xp + 8 * grp + 4);
        rx2 = *(const float4*)(xp + 32 + 8 * grp);
        rx3 = *(const float4*)(xp + 36 + 8 * grp);
    }

    // ---- per-mode constants (PRECISE: w^64 errors compound x63 in the scan) ----
    if (tid < NNc) {
        int n = tid;
        float dtv = expf(log_dt[h]);
        float Ar = -expf(log_A_real[h * NNc + n]);
        float Ai = A_imag[h * NNc + n];
        float ar = Ar * dtv, ai = Ai * dtv;
        cAr[n] = ar; cAi[n] = ai;
        float er = expf(ar), sn, cs;
        sincosf(ai, &sn, &cs);
        float numr = er * cs - 1.f, numi = er * sn;
        float inv = 1.f / (Ar * Ar + Ai * Ai);
        float fr = (numr * Ar + numi * Ai) * inv;
        float fi = (numi * Ar - numr * Ai) * inv;
        float Ccr = Cmat[(h * NNc + n) * 2 + 0];
        float Cci = Cmat[(h * NNc + n) * 2 + 1];
        c2R[n] = 2.f * (Ccr * fr - Cci * fi);
        c2I[n] = 2.f * (Ccr * fi + Cci * fr);
        float e64 = expf(64.f * ar), s64, c64;
        sincosf(64.f * ai, &s64, &c64);
        cWSr[n] = e64 * c64; cWSi[n] = e64 * s64;   // w^64
    }
    __syncthreads();

    // ---- Kpart (into Sscan scratch) + Wt + Wp generation (fast intrinsics) ----
    {
        int p = tid >> 2, q = tid & 3;
        float acc = 0.f;
#pragma unroll
        for (int i = 0; i < 8; i++) {
            int n = 8 * q + i;
            float fp = (float)p;
            float e = __expf(cAr[n] * fp);
            float sn = __sinf(cAi[n] * fp), cs = __cosf(cAi[n] * fp);
            acc += e * (c2R[n] * cs - c2I[n] * sn);
        }
        Sscan[p * 4 + q] = acc;
    }
#pragma unroll
    for (int m = 0; m < 2; m++) {
        int u = tid + 256 * m;
        int r = u >> 3, jc = u & 7;
        {   // Wt row r = out mode-comp: w_n^{63-j}
            int n = r >> 1, im = r & 1;
            s8v hv, lv;
#pragma unroll
            for (int i = 0; i < 8; i++) {
                float p = (float)(63 - (jc * 8 + i));
                float e = __expf(cAr[n] * p);
                float sn = __sinf(cAi[n] * p), cs = __cosf(cAi[n] * p);
                unsigned short hh, ll;
                split2(e * (im ? sn : cs), &hh, &ll);
                hv[i] = (short)hh; lv[i] = (short)ll;
            }
            int idx = SWB(r, jc * 8);
            *(s8v*)&WtH[idx] = hv;
            *(s8v*)&WtL[idx] = lv;
        }
        {   // Wp row r = t: col c: Re(w^{t+1}) / -Im(w^{t+1})  (hi only)
            float p = (float)(r + 1);
            s8v hv;
#pragma unroll
            for (int i = 0; i < 8; i++) {
                int c = jc * 8 + i;
                int n = c >> 1;
                float e = __expf(cAr[n] * p);
                float sn = __sinf(cAi[n] * p), cs = __cosf(cAi[n] * p);
                hv[i] = (short)bf16_rne(e * ((c & 1) ? -sn : cs));
            }
            *(s8v*)&WpH[SWB(r, jc * 8)] = hv;
        }
    }
    __syncthreads();

    if (tid < 64) {
        float k = Sscan[tid * 4] + Sscan[tid * 4 + 1] + Sscan[tid * 4 + 2] + Sscan[tid * 4 + 3];
        if (tid == 0) k += Dvec[h];
        Ktap[tid] = k;
    }
    __syncthreads();

    // ---- Tt (hi only): row t, k=j: K[t-j] ----
#pragma unroll
    for (int m = 0; m < 2; m++) {
        int u = tid + 256 * m;
        int r = u >> 3, jc = u & 7;
        s8v hv;
#pragma unroll
        for (int i = 0; i < 8; i++) {
            int j = jc * 8 + i;
            hv[i] = (short)bf16_rne((j <= r) ? Ktap[r - j] : 0.f);
        }
        *(s8v*)&TtH[SWB(r, jc * 8)] = hv;
    }
    __syncthreads();

    // ---- batch loop ----
    for (int b = 0; b < Bc; b++) {
        s8v xh0, xl0, xh1, xl1;
        cvt8(rx0, rx1, &xh0, &xl0);
        cvt8(rx2, rx3, &xh1, &xl1);

        if (b < Bc - 1) {
            const float* xp = xT + (size_t)((b + 1) * Hc + h) * Lc + (16 * w + l15) * 64;
            rx0 = *(const float4*)(xp + 8 * grp);
            rx1 = *(const float4*)(xp + 8 * grp + 4);
            rx2 = *(const float4*)(xp + 32 + 8 * grp);
            rx3 = *(const float4*)(xp + 36 + 8 * grp);
        }

        // Phase 1: S = X * Wrev (bf16x3). D rows = chunk s, cols = mode-comp m.
        f4v acc[4];
#pragma unroll
        for (int tj = 0; tj < 4; tj++) {
            int row = tj * 16 + l15;
            int i0 = SWB(row, 8 * grp);
            int i1 = SWB(row, 32 + 8 * grp);
            s8v bh0 = *(const s8v*)&WtH[i0];
            s8v bh1 = *(const s8v*)&WtH[i1];
            s8v bl0 = *(const s8v*)&WtL[i0];
            s8v bl1 = *(const s8v*)&WtL[i1];
            f4v a = {0.f, 0.f, 0.f, 0.f};
            a = MFMA(xh0, bh0, a);
            a = MFMA(xh1, bh1, a);
            a = MFMA(xl0, bh0, a);
            a = MFMA(xl1, bh1, a);
            a = MFMA(xh0, bl0, a);
            a = MFMA(xh1, bl1, a);
            acc[tj] = a;
        }
        // store S transposed: Sscan[m][s]
#pragma unroll
        for (int tj = 0; tj < 4; tj++) {
#pragma unroll
            for (int r2 = 0; r2 < 4; r2++) {
                Sscan[(tj * 16 + l15) * 65 + 16 * w + 4 * grp + r2] = acc[tj][r2];
            }
        }
        __syncthreads();   // (a)

        // ---- wave-parallel Kogge-Stone scan: wave w owns modes 8w..8w+7, lane = chunk ----
        {
            float Pr[8], Pi[8], qr[8], qi[8];
#pragma unroll
            for (int i = 0; i < 8; i++) {
                int m0 = (16 * w + 2 * i) * 65;
                Pr[i] = Sscan[m0 + l];
                Pi[i] = Sscan[m0 + 65 + l];
                int n = 8 * w + i;
                qr[i] = cWSr[n]; qi[i] = cWSi[n];
            }
#pragma unroll
            for (int d = 1; d < 64; d <<= 1) {
#pragma unroll
                for (int i = 0; i < 8; i++) {
                    float tr = __shfl_up(Pr[i], (unsigned)d, 64);
                    float ti = __shfl_up(Pi[i], (unsigned)d, 64);
                    if (l >= d) {
                        Pr[i] = fmaf(qr[i], tr, fmaf(-qi[i], ti, Pr[i]));
                        Pi[i] = fmaf(qr[i], ti, fmaf( qi[i], tr, Pi[i]));
                    }
                }
                if (d < 32) {
#pragma unroll
                    for (int i = 0; i < 8; i++) {
                        float nr = fmaf(qr[i], qr[i], -(qi[i] * qi[i]));
                        float ni = 2.f * qr[i] * qi[i];
                        qr[i] = nr; qi[i] = ni;
                    }
                }
            }
            // G_s = P_{s-1}; E = 2Cw (x) G
#pragma unroll
            for (int i = 0; i < 8; i++) {
                float Gr = __shfl_up(Pr[i], 1u, 64);
                float Gi = __shfl_up(Pi[i], 1u, 64);
                if (l == 0) { Gr = 0.f; Gi = 0.f; }
                int n = 8 * w + i;
                float cr = c2R[n], ci = c2I[n];
                float er = fmaf(cr, Gr, -(ci * Gi));
                float ei = fmaf(cr, Gi,  (ci * Gr));
                int m0 = (16 * w + 2 * i) * 65;
                Sscan[m0 + l]      = er;
                Sscan[m0 + 65 + l] = ei;
            }
        }
        __syncthreads();   // (b)

        // E fragments: A rows = chunk 16w+l15, k = mode-comp
        s8v eh0, el0, eh1, el1;
        {
            float ev[16];
#pragma unroll
            for (int i = 0; i < 8; i++)
                ev[i] = Sscan[(8 * grp + i) * 65 + 16 * w + l15];
#pragma unroll
            for (int i = 0; i < 8; i++)
                ev[8 + i] = Sscan[(32 + 8 * grp + i) * 65 + 16 * w + l15];
#pragma unroll
            for (int i = 0; i < 8; i++) {
                unsigned short hh, ll;
                split2(ev[i], &hh, &ll);
                eh0[i] = (short)hh; el0[i] = (short)ll;
                split2(ev[8 + i], &hh, &ll);
                eh1[i] = (short)hh; el1[i] = (short)ll;
            }
        }
        __syncthreads();   // (c) — Sscan free for next batch

        // Phase 3: Y = X*T + E*Wp (bf16x2 each)
        float* yp = xT + ((size_t)b * Hc + h) * Lc;
#pragma unroll
        for (int tj = 0; tj < 4; tj++) {
            int row = tj * 16 + l15;
            int i0 = SWB(row, 8 * grp);
            int i1 = SWB(row, 32 + 8 * grp);
            s8v th0 = *(const s8v*)&TtH[i0];
            s8v th1 = *(const s8v*)&TtH[i1];
            s8v ph0 = *(const s8v*)&WpH[i0];
            s8v ph1 = *(const s8v*)&WpH[i1];
            f4v a = {0.f, 0.f, 0.f, 0.f};
            a = MFMA(xh0, th0, a);
            a = MFMA(xh1, th1, a);
            a = MFMA(xl0, th0, a);
            a = MFMA(xl1, th1, a);
            a = MFMA(eh0, ph0, a);
            a = MFMA(eh1, ph1, a);
            a = MFMA(el0, ph0, a);
            a = MFMA(el1, ph1, a);
#pragma unroll
            for (int r2 = 0; r2 < 4; r2++) {
                yp[(16 * w + 4 * grp + r2) * 64 + tj * 16 + l15] = a[r2];
            }
        }
    }
}

extern "C" void kernel_launch(void* const* d_in, const int* in_sizes, int n_in,
                              void* d_out, int out_size, void* d_ws, size_t ws_size,
                              hipStream_t stream) {
    const float* x          = (const float*)d_in[0];
    const float* log_dt     = (const float*)d_in[1];
    const float* log_A_real = (const float*)d_in[2];
    const float* A_imag     = (const float*)d_in[3];
    const float* Cmat       = (const float*)d_in[4];
    const float* Dvec       = (const float*)d_in[5];
    float* out = (float*)d_out;
    float* ws  = (float*)d_ws;

    const size_t need = (size_t)Bc * Hc * Lc * sizeof(float);   // 64 MiB
    if (ws_size < need) return;

    // x [B][L][H] -> ws (xT) [B][H][L]
    transpose_v4<<<dim3(Hc / 64, Lc / 64, Bc), 256, 0, stream>>>(x, ws, Lc, Hc);
    // fused SSM per h (all batches); writes yT in place
    s4d_mfma2<<<Hc, 256, 0, stream>>>(ws, log_dt, log_A_real, A_imag, Cmat, Dvec);
    // ws (yT) [B][H][L] -> out [B][L][H]
    transpose_v4<<<dim3(Lc / 64, Hc / 64, Bc), 256, 0, stream>>>(ws, out, Hc, Lc);
}